// Round 3
// baseline (90.451 us; speedup 1.0000x reference)
//
#include <hip/hip_runtime.h>
#include <cstdint>
#include <cstddef>

// x[64][1024][32] f32, W[1024][32] f32, b[1024] f32 -> out[64][1024][1024] f32
#define BATCH   64
#define SEQLEN  1024
#define KDIM    32
#define ODIM    1024
#define NTOK    (BATCH * SEQLEN)

typedef __attribute__((ext_vector_type(8))) short bf16x8;   // 8 bf16 = 4 VGPRs
typedef __attribute__((ext_vector_type(4))) float f32x4;

// exact f32 -> bf16 truncation; exact for integer-valued f32 with |v| <= 255
// and for ternary {-1,0,1}
__device__ __forceinline__ unsigned short f32_to_bf16_exact(float f) {
    union { float f; unsigned int u; } cv; cv.f = f;
    return (unsigned short)(cv.u >> 16);
}

// ---------------------------------------------------------------------------
// Kernel 1: W |.| partial sums. 8 blocks x 256 threads x 16 contiguous elems.
// Deterministic fixed-order tree reduce; partial[blockIdx] written once.
// ---------------------------------------------------------------------------
__global__ __launch_bounds__(256) void wpartial_kernel(const float* __restrict__ W,
                                                       float* __restrict__ partial) {
    __shared__ float red[256];
    const int t = threadIdx.x;
    const float4* W4 = reinterpret_cast<const float4*>(W) + (size_t)blockIdx.x * 1024 + t * 4;
    float acc = 0.f;
    #pragma unroll
    for (int j = 0; j < 4; ++j) {
        float4 v = W4[j];
        acc += fabsf(v.x) + fabsf(v.y) + fabsf(v.z) + fabsf(v.w);
    }
    red[t] = acc;
    __syncthreads();
    for (int step = 128; step > 0; step >>= 1) {
        if (t < step) red[t] += red[t + step];
        __syncthreads();
    }
    if (t == 0) partial[blockIdx.x] = red[0];
}

// ---------------------------------------------------------------------------
// Kernel 2: fully fused BitLinear: on-the-fly W ternary quant + on-the-fly
// per-token activation quant + MFMA GEMM + bias + in-register f32 positional
// encoding + nontemporal f32x4 stores.
//
// D(M=o 16, N=token 16, K=32) via mfma_f32_16x16x32_bf16.
// Block: 4 waves, tile = 16 s x 64 o, b split 4 waves x 16.
// Grid: 64 s-blocks x 16 o-blocks = 1024 blocks (4 blocks/CU).
// Fragment maps (guide-verified): A row=lane&15, k=(lane>>4)*8+j;
// B col=lane&15, k=(lane>>4)*8+j; D col=lane&15 (token), row=(lane>>4)*4+reg (o).
// ---------------------------------------------------------------------------
__global__ __launch_bounds__(256) void bitgemm_fused(
    const float* __restrict__ x,        // [65536][32]
    const float* __restrict__ W,        // [1024][32]
    const float* __restrict__ bias,     // [1024]
    const float* __restrict__ partial,  // [8]
    float* __restrict__ out)            // [65536][1024]
{
    const int lane = threadIdx.x & 63;
    const int wid  = threadIdx.x >> 6;
    const int l15  = lane & 15;
    const int hi   = lane >> 4;              // 0..3

    const int oblk = blockIdx.x & 15;
    const int sblk = blockIdx.x >> 4;
    const int o0   = oblk * 64;
    const int s0   = sblk * 16;

    // ---- weight scale from the 8 partials (uniform scalar path) ----
    float tot = 0.f;
    #pragma unroll
    for (int p = 0; p < 8; ++p) tot += partial[p];
    const float mean = tot * (1.0f / 32768.0f);
    const float rw = fmaxf(mean, 1e-5f);     // 1/scale_w
    const float sc = 1.0f / rw;              // scale_w

    // ---- A fragments: ternary-quantize W directly into MFMA layout ----
    bf16x8 afrag[4];
    #pragma unroll
    for (int f = 0; f < 4; ++f) {
        const float* wr = W + (size_t)(o0 + f * 16 + l15) * KDIM + hi * 8;
        float4 wa = *reinterpret_cast<const float4*>(wr);
        float4 wb = *reinterpret_cast<const float4*>(wr + 4);
        float e[8] = {wa.x, wa.y, wa.z, wa.w, wb.x, wb.y, wb.z, wb.w};
        union { bf16x8 v; unsigned short s[8]; } u;
        #pragma unroll
        for (int j = 0; j < 8; ++j) {
            float q = fminf(fmaxf(rintf(e[j] * sc), -1.0f), 1.0f);  // {-1,0,1}
            u.s[j] = f32_to_bf16_exact(q);
        }
        afrag[f] = u.v;
    }

    // ---- bias + positional encoding, in-register f32 (hoisted) ----
    // pe(s,o) = sin/cos(s * 10000^(-(o&~1)/1024)); exp2f arg err <= 8e-7
    // -> angle err <= ~6e-5 rad, far below the 7.2e-2 threshold.
    const float C = -0.012976281620653759f;  // -log2(10000)/1024
    const float sf = (float)(s0 + l15);
    f32x4 addf[4];
    #pragma unroll
    for (int f = 0; f < 4; ++f) {
        const int oe = o0 + f * 16 + hi * 4;          // multiple of 4 (even)
        f32x4 bv = *reinterpret_cast<const f32x4*>(bias + oe);
        float inv0 = exp2f(C * (float)oe);
        float inv1 = exp2f(C * (float)(oe + 2));
        float a0 = sf * inv0, a1 = sf * inv1;
        addf[f][0] = bv[0] + sinf(a0);
        addf[f][1] = bv[1] + cosf(a0);
        addf[f][2] = bv[2] + sinf(a1);
        addf[f][3] = bv[3] + cosf(a1);
    }

    // ---- b-loop: on-the-fly activation quant + MFMA + epilogue ----
    for (int i = 0; i < 16; ++i) {
        const int b   = wid * 16 + i;
        const int tok = b * SEQLEN + s0 + l15;
        // wave reads a fully contiguous 2 KB (16 token rows of 128 B)
        const float* xr = x + (size_t)tok * KDIM + hi * 8;
        float4 xa = *reinterpret_cast<const float4*>(xr);
        float4 xb = *reinterpret_cast<const float4*>(xr + 4);

        float am = fmaxf(fmaxf(fmaxf(fabsf(xa.x), fabsf(xa.y)),
                               fmaxf(fabsf(xa.z), fabsf(xa.w))),
                         fmaxf(fmaxf(fabsf(xb.x), fabsf(xb.y)),
                               fmaxf(fabsf(xb.z), fabsf(xb.w))));
        // lanes {l15, l15+16, l15+32, l15+48} hold the same token's 4 k-slices
        am = fmaxf(am, __shfl_xor(am, 16));
        am = fmaxf(am, __shfl_xor(am, 32));
        am = fmaxf(am, 1e-5f);
        const float scale = 127.0f / am;     // |v*scale| <= 127: clip can't bind

        float e[8] = {xa.x, xa.y, xa.z, xa.w, xb.x, xb.y, xb.z, xb.w};
        union { bf16x8 v; unsigned short s[8]; } u;
        #pragma unroll
        for (int j = 0; j < 8; ++j)
            u.s[j] = f32_to_bf16_exact(rintf(e[j] * scale));  // int in [-127,127]
        const float rxw = am * (1.0f / 127.0f) * rw;          // combined 1/scales

        f32x4 acc[4];
        #pragma unroll
        for (int f = 0; f < 4; ++f) {
            acc[f] = (f32x4){0.f, 0.f, 0.f, 0.f};
            acc[f] = __builtin_amdgcn_mfma_f32_16x16x32_bf16(afrag[f], u.v, acc[f], 0, 0, 0);
        }

        float* op = out + (size_t)tok * ODIM + o0 + hi * 4;
        #pragma unroll
        for (int f = 0; f < 4; ++f) {
            f32x4 r;
            #pragma unroll
            for (int j = 0; j < 4; ++j)
                r[j] = fmaf(acc[f][j], rxw, addf[f][j]);
            // output is never re-read: keep it out of L2
            __builtin_nontemporal_store(r, reinterpret_cast<f32x4*>(op + f * 16));
        }
    }
}

// ---------------------------------------------------------------------------
extern "C" void kernel_launch(void* const* d_in, const int* in_sizes, int n_in,
                              void* d_out, int out_size, void* d_ws, size_t ws_size,
                              hipStream_t stream) {
    const float* x = (const float*)d_in[0];   // [64][1024][32]
    const float* W = (const float*)d_in[1];   // [1024][32]
    const float* b = (const float*)d_in[2];   // [1024]
    float* out = (float*)d_out;

    float* partial = (float*)d_ws;            // 8 floats

    wpartial_kernel<<<8, 256, 0, stream>>>(W, partial);
    bitgemm_fused<<<SEQLEN / 16 * (ODIM / 64), 256, 0, stream>>>(x, W, b, partial, out);
}